// Round 8
// baseline (176.312 us; speedup 1.0000x reference)
//
#include <hip/hip_runtime.h>

#define DD 2048
#define HH 512
#define NTOK 16384

typedef __attribute__((ext_vector_type(8))) short short8_t;
typedef __attribute__((ext_vector_type(4))) short short4_t;
typedef __attribute__((ext_vector_type(4))) float f32x4;

static __device__ __forceinline__ short f2bf(float f) {
    union { float f; unsigned u; } v; v.f = f;
    unsigned r = (v.u + 0x7fffu + ((v.u >> 16) & 1u)) >> 16;
    return (short)r;
}
static __device__ __forceinline__ float bf2f(unsigned short s) {
    union { unsigned u; float f; } v; v.u = (unsigned)s << 16;
    return v.f;
}

// async global->LDS, 16B/lane. dest base wave-uniform; HW adds lane*16.
static __device__ __forceinline__ void gl16(const short* g, short* l) {
    __builtin_amdgcn_global_load_lds(
        (const __attribute__((address_space(1))) unsigned int*)g,
        (__attribute__((address_space(3))) unsigned int*)l, 16, 0, 0);
}

// ---- prep: blocks 0..127 Wg=Wd*gamma + c2; 128..383 Wu->bf16;
//            384..16767: LN-normalize one token row -> xn bf16, save mu/sd ----
__global__ __launch_bounds__(256) void k_prep(
    const float* __restrict__ Wd, const float* __restrict__ g,
    const float* __restrict__ be, const float* __restrict__ Wu,
    const float* __restrict__ x,
    short* __restrict__ Wg, short* __restrict__ Wub,
    float* __restrict__ c2, short* __restrict__ xn,
    float* __restrict__ muv, float* __restrict__ sdv)
{
    __shared__ float ss[4], sq[4];
    int bid = blockIdx.x;
    int w = threadIdx.x >> 6, lane = threadIdx.x & 63;
    if (bid < 128) {
        int h = bid * 4 + w;
        const float* wr = Wd + (size_t)h * DD;
        float s2 = 0.f;
        for (int i = 0; i < 8; i++) {
            int col = i * 256 + lane * 4;
            float4 wv = *(const float4*)(wr + col);
            float4 gv = *(const float4*)(g + col);
            float4 bv = *(const float4*)(be + col);
            s2 += bv.x * wv.x + bv.y * wv.y + bv.z * wv.z + bv.w * wv.w;
            short4_t o;
            o[0] = f2bf(wv.x * gv.x); o[1] = f2bf(wv.y * gv.y);
            o[2] = f2bf(wv.z * gv.z); o[3] = f2bf(wv.w * gv.w);
            *(short4_t*)(Wg + (size_t)h * DD + col) = o;
        }
        for (int m = 1; m < 64; m <<= 1) s2 += __shfl_xor(s2, m);
        if (lane == 0) c2[h] = s2;
    } else if (bid < 384) {
        int b = bid - 128;  // 0..255
        for (int r = 0; r < 4; r++) {
            int i = (b * 4 + r) * 1024 + threadIdx.x * 4;
            float4 v = *(const float4*)(Wu + i);
            short4_t o;
            o[0] = f2bf(v.x); o[1] = f2bf(v.y); o[2] = f2bf(v.z); o[3] = f2bf(v.w);
            *(short4_t*)(Wub + i) = o;
        }
    } else {
        int row = bid - 384;
        const float* xr = x + (size_t)row * DD + threadIdx.x * 8;
        float4 a = *(const float4*)xr;
        float4 b = *(const float4*)(xr + 4);
        float s = a.x + a.y + a.z + a.w + b.x + b.y + b.z + b.w;
        float q = a.x * a.x + a.y * a.y + a.z * a.z + a.w * a.w
                + b.x * b.x + b.y * b.y + b.z * b.z + b.w * b.w;
        for (int m = 1; m < 64; m <<= 1) { s += __shfl_xor(s, m); q += __shfl_xor(q, m); }
        if (lane == 0) { ss[w] = s; sq[w] = q; }
        __syncthreads();
        float S = ss[0] + ss[1] + ss[2] + ss[3];
        float Q = sq[0] + sq[1] + sq[2] + sq[3];
        float mu = S * (1.f / DD);
        float ve = Q * (1.f / DD) - mu * mu + 1e-5f;
        float rs = rsqrtf(ve);
        if (threadIdx.x == 0) { muv[row] = mu; sdv[row] = ve * rs; }
        short8_t o;
        o[0] = f2bf((a.x - mu) * rs); o[1] = f2bf((a.y - mu) * rs);
        o[2] = f2bf((a.z - mu) * rs); o[3] = f2bf((a.w - mu) * rs);
        o[4] = f2bf((b.x - mu) * rs); o[5] = f2bf((b.y - mu) * rs);
        o[6] = f2bf((b.z - mu) * rs); o[7] = f2bf((b.w - mu) * rs);
        *(short8_t*)(xn + (size_t)row * DD + threadIdx.x * 8) = o;
    }
}

// ---- k_down: hid = relu(xn @ Wg^T + c2 + bd), 128m x 64n, BK=64, dbuf ----
__global__ __launch_bounds__(256, 3) void k_down(
    const short* __restrict__ xn, const short* __restrict__ Wg,
    const float* __restrict__ c2, const float* __restrict__ bd,
    short* __restrict__ hid)
{
    __shared__ __align__(16) char smem[49152];
    short* sA = (short*)smem;            // [2][128*64]  32 KB
    short* sB = (short*)(smem + 32768);  // [2][64*64]   16 KB

    // bijective XCD swizzle (nwg=1024), n fastest
    int bid = blockIdx.x;
    int nb = (bid & 7) * 128 + (bid >> 3);
    const int n0 = (nb & 7) * 64;
    const int m0 = (nb >> 3) * 128;

    const int tid = threadIdx.x, lane = tid & 63, w = tid >> 6;
    const int l15 = lane & 15, rg = lane >> 4;
    const int wm = w;   // 4 waves: 32 rows x 64 cols each

    auto stage = [&](int b, int kb) {
#pragma unroll
        for (int i = 0; i < 4; i++) {        // A: 1024 chunks
            int ch = i * 256 + tid;
            int r = ch >> 3, c = ch & 7;
            gl16(xn + (size_t)(m0 + r) * DD + kb + ((c ^ (r & 7)) << 3),
                 sA + b * 8192 + (i * 256 + (w << 6)) * 8);
        }
#pragma unroll
        for (int i = 0; i < 2; i++) {        // B: 512 chunks
            int ch = i * 256 + tid;
            int r = ch >> 3, c = ch & 7;
            gl16(Wg + (size_t)(n0 + r) * DD + kb + ((c ^ (r & 7)) << 3),
                 sB + b * 4096 + (i * 256 + (w << 6)) * 8);
        }
    };

    f32x4 acc[2][4];
#pragma unroll
    for (int i = 0; i < 2; i++)
#pragma unroll
        for (int j = 0; j < 4; j++) acc[i][j] = (f32x4){0.f, 0.f, 0.f, 0.f};

    stage(0, 0);
    __syncthreads();

    for (int t = 0; t < 32; t++) {
        int cur = t & 1, nxt = cur ^ 1;
        if (t < 31) stage(nxt, (t + 1) * 64);
#pragma unroll
        for (int kk = 0; kk < 2; kk++) {
            int kc = kk * 4 + rg;
            short8_t af[2], bf[4];
#pragma unroll
            for (int mi = 0; mi < 2; mi++) {
                int rr = wm * 32 + mi * 16 + l15;
                af[mi] = *(const short8_t*)(sA + cur * 8192 + rr * 64 + ((kc ^ (rr & 7)) << 3));
            }
#pragma unroll
            for (int ni = 0; ni < 4; ni++) {
                int rr = ni * 16 + l15;
                bf[ni] = *(const short8_t*)(sB + cur * 4096 + rr * 64 + ((kc ^ (rr & 7)) << 3));
            }
#pragma unroll
            for (int mi = 0; mi < 2; mi++)
#pragma unroll
                for (int ni = 0; ni < 4; ni++)
                    acc[mi][ni] = __builtin_amdgcn_mfma_f32_16x16x32_bf16(
                        af[mi], bf[ni], acc[mi][ni], 0, 0, 0);
        }
        __syncthreads();
    }

    // epilogue: + c2 + bd, relu -> hid bf16
#pragma unroll
    for (int ni = 0; ni < 4; ni++) {
        int h = n0 + ni * 16 + l15;
        float C = c2[h] + bd[h];
#pragma unroll
        for (int mi = 0; mi < 2; mi++) {
#pragma unroll
            for (int j = 0; j < 4; j++) {
                int rowL = wm * 32 + mi * 16 + rg * 4 + j;
                float v = acc[mi][ni][j] + C;
                v = v > 0.f ? v : 0.f;
                hid[(size_t)(m0 + rowL) * HH + h] = f2bf(v);
            }
        }
    }
}

// ---- k_up: out = xn*sd + mu + bu + hid @ Wu^T, 128m x 64n, BK=64, dbuf ----
__global__ __launch_bounds__(256, 3) void k_up(
    const short* __restrict__ xn, const short* __restrict__ hid,
    const short* __restrict__ Wub, const float* __restrict__ bu,
    const float* __restrict__ muv, const float* __restrict__ sdv,
    float* __restrict__ out)
{
    __shared__ __align__(16) char smem[50176];
    short* sA  = (short*)smem;             // [2][128*64]  32 KB (reused as C f32)
    short* sB  = (short*)(smem + 32768);   // [2][64*64]   16 KB
    float* s_mu = (float*)(smem + 49152);  // [128]
    float* s_sd = (float*)(smem + 49664);  // [128]

    // bijective XCD swizzle (nwg=4096), n fastest
    int bid = blockIdx.x;
    int nb = (bid & 7) * 512 + (bid >> 3);
    const int n0 = (nb & 31) * 64;
    const int m0 = (nb >> 5) * 128;

    const int tid = threadIdx.x, lane = tid & 63, w = tid >> 6;
    const int l15 = lane & 15, rg = lane >> 4;
    const int wm = w;

    auto stage = [&](int b, int kb) {
#pragma unroll
        for (int i = 0; i < 4; i++) {
            int ch = i * 256 + tid;
            int r = ch >> 3, c = ch & 7;
            gl16(hid + (size_t)(m0 + r) * HH + kb + ((c ^ (r & 7)) << 3),
                 sA + b * 8192 + (i * 256 + (w << 6)) * 8);
        }
#pragma unroll
        for (int i = 0; i < 2; i++) {
            int ch = i * 256 + tid;
            int r = ch >> 3, c = ch & 7;
            gl16(Wub + (size_t)(n0 + r) * HH + kb + ((c ^ (r & 7)) << 3),
                 sB + b * 4096 + (i * 256 + (w << 6)) * 8);
        }
    };

    f32x4 acc[2][4];
#pragma unroll
    for (int i = 0; i < 2; i++)
#pragma unroll
        for (int j = 0; j < 4; j++) acc[i][j] = (f32x4){0.f, 0.f, 0.f, 0.f};

    stage(0, 0);
    if (tid < 128) { s_mu[tid] = muv[m0 + tid]; s_sd[tid] = sdv[m0 + tid]; }
    __syncthreads();

    for (int t = 0; t < 8; t++) {
        int cur = t & 1, nxt = cur ^ 1;
        if (t < 7) stage(nxt, (t + 1) * 64);
#pragma unroll
        for (int kk = 0; kk < 2; kk++) {
            int kc = kk * 4 + rg;
            short8_t af[2], bf[4];
#pragma unroll
            for (int mi = 0; mi < 2; mi++) {
                int rr = wm * 32 + mi * 16 + l15;
                af[mi] = *(const short8_t*)(sA + cur * 8192 + rr * 64 + ((kc ^ (rr & 7)) << 3));
            }
#pragma unroll
            for (int ni = 0; ni < 4; ni++) {
                int rr = ni * 16 + l15;
                bf[ni] = *(const short8_t*)(sB + cur * 4096 + rr * 64 + ((kc ^ (rr & 7)) << 3));
            }
#pragma unroll
            for (int mi = 0; mi < 2; mi++)
#pragma unroll
                for (int ni = 0; ni < 4; ni++)
                    acc[mi][ni] = __builtin_amdgcn_mfma_f32_16x16x32_bf16(
                        af[mi], bf[ni], acc[mi][ni], 0, 0, 0);
        }
        __syncthreads();
    }

    // ---- epilogue: acc -> swizzled LDS f32 tile -> coalesced dwordx4 stores ----
    float* C = (float*)smem;  // [128][64], reuses sA region (32 KB)
#pragma unroll
    for (int ni = 0; ni < 4; ni++)
#pragma unroll
        for (int mi = 0; mi < 2; mi++)
#pragma unroll
            for (int j = 0; j < 4; j++) {
                int row = wm * 32 + mi * 16 + rg * 4 + j;
                int colsw = (ni * 16 + l15) ^ ((row & 7) << 2);
                C[row * 64 + colsw] = acc[mi][ni][j];
            }
    __syncthreads();

    {
        const int row = tid >> 1, half = tid & 1, r7 = row & 7;
        const float mu = s_mu[row], sd = s_sd[row];
        const size_t rb = (size_t)(m0 + row) * DD + n0 + half * 32;
        const float* burow = bu + n0 + half * 32;
#pragma unroll
        for (int i = 0; i < 8; i++) {
            f32x4 c = *(const f32x4*)&C[row * 64 + half * 32 + 4 * (i ^ r7)];
            short4_t xv = *(const short4_t*)(xn + rb + i * 4);
            float4 bv = *(const float4*)(burow + i * 4);
            f32x4 o;
            o[0] = fmaf(bf2f((unsigned short)xv[0]), sd, mu) + bv.x + c[0];
            o[1] = fmaf(bf2f((unsigned short)xv[1]), sd, mu) + bv.y + c[1];
            o[2] = fmaf(bf2f((unsigned short)xv[2]), sd, mu) + bv.z + c[2];
            o[3] = fmaf(bf2f((unsigned short)xv[3]), sd, mu) + bv.w + c[3];
            *(f32x4*)&out[rb + i * 4] = o;
        }
    }
}

extern "C" void kernel_launch(void* const* d_in, const int* in_sizes, int n_in,
                              void* d_out, int out_size, void* d_ws, size_t ws_size,
                              hipStream_t stream) {
    const float* x     = (const float*)d_in[0];
    const float* gamma = (const float*)d_in[1];
    const float* beta  = (const float*)d_in[2];
    const float* Wd_f  = (const float*)d_in[3];  // [H, D]
    const float* bd    = (const float*)d_in[4];
    const float* Wu_f  = (const float*)d_in[5];  // [D, H]
    const float* bu    = (const float*)d_in[6];

    short* Wg  = (short*)d_ws;                     // 2 MB bf16 [H][D] (Wd*gamma)
    short* Wub = Wg + (size_t)HH * DD;             // 2 MB bf16 [D][H]
    float* c2  = (float*)(Wub + (size_t)DD * HH);  // 2 KB
    float* muv = c2 + HH;                          // 64 KB
    float* sdv = muv + NTOK;                       // 64 KB
    short* hid = (short*)(sdv + NTOK);             // 16 MB bf16 [NTOK][H]
    short* xn  = hid + (size_t)NTOK * HH;          // 64 MB bf16 [NTOK][D]

    k_prep<<<384 + NTOK, 256, 0, stream>>>(Wd_f, gamma, beta, Wu_f, x,
                                           Wg, Wub, c2, xn, muv, sdv);
    k_down<<<(NTOK / 128) * (HH / 64), 256, 0, stream>>>(xn, Wg, c2, bd, hid);
    k_up<<<(NTOK / 128) * (DD / 64), 256, 0, stream>>>(xn, hid, Wub, bu,
                                                       muv, sdv, (float*)d_out);
}

// Round 9
// 167.371 us; speedup vs baseline: 1.0534x; 1.0534x over previous
//
#include <hip/hip_runtime.h>

#define DD 2048
#define HH 512
#define NTOK 16384

typedef __attribute__((ext_vector_type(8))) short short8_t;
typedef __attribute__((ext_vector_type(4))) short short4_t;
typedef __attribute__((ext_vector_type(4))) float f32x4;

static __device__ __forceinline__ short f2bf(float f) {
    union { float f; unsigned u; } v; v.f = f;
    unsigned r = (v.u + 0x7fffu + ((v.u >> 16) & 1u)) >> 16;
    return (short)r;
}
static __device__ __forceinline__ float bf2f(unsigned short s) {
    union { unsigned u; float f; } v; v.u = (unsigned)s << 16;
    return v.f;
}

// async global->LDS, 16B/lane. dest base wave-uniform; HW adds lane*16.
static __device__ __forceinline__ void gl16(const short* g, short* l) {
    __builtin_amdgcn_global_load_lds(
        (const __attribute__((address_space(1))) unsigned int*)g,
        (__attribute__((address_space(3))) unsigned int*)l, 16, 0, 0);
}

// ---- prep: blocks 0..127 Wg=Wd*gamma + c2; 128..383 Wu->bf16;
//            384..16767: LN-normalize one token row -> xn bf16, save mu/sd ----
__global__ __launch_bounds__(256) void k_prep(
    const float* __restrict__ Wd, const float* __restrict__ g,
    const float* __restrict__ be, const float* __restrict__ Wu,
    const float* __restrict__ x,
    short* __restrict__ Wg, short* __restrict__ Wub,
    float* __restrict__ c2, short* __restrict__ xn,
    float* __restrict__ muv, float* __restrict__ sdv)
{
    __shared__ float ss[4], sq[4];
    int bid = blockIdx.x;
    int w = threadIdx.x >> 6, lane = threadIdx.x & 63;
    if (bid < 128) {
        int h = bid * 4 + w;
        const float* wr = Wd + (size_t)h * DD;
        float s2 = 0.f;
        for (int i = 0; i < 8; i++) {
            int col = i * 256 + lane * 4;
            float4 wv = *(const float4*)(wr + col);
            float4 gv = *(const float4*)(g + col);
            float4 bv = *(const float4*)(be + col);
            s2 += bv.x * wv.x + bv.y * wv.y + bv.z * wv.z + bv.w * wv.w;
            short4_t o;
            o[0] = f2bf(wv.x * gv.x); o[1] = f2bf(wv.y * gv.y);
            o[2] = f2bf(wv.z * gv.z); o[3] = f2bf(wv.w * gv.w);
            *(short4_t*)(Wg + (size_t)h * DD + col) = o;
        }
        for (int m = 1; m < 64; m <<= 1) s2 += __shfl_xor(s2, m);
        if (lane == 0) c2[h] = s2;
    } else if (bid < 384) {
        int b = bid - 128;  // 0..255
        for (int r = 0; r < 4; r++) {
            int i = (b * 4 + r) * 1024 + threadIdx.x * 4;
            float4 v = *(const float4*)(Wu + i);
            short4_t o;
            o[0] = f2bf(v.x); o[1] = f2bf(v.y); o[2] = f2bf(v.z); o[3] = f2bf(v.w);
            *(short4_t*)(Wub + i) = o;
        }
    } else {
        int row = bid - 384;
        const float* xr = x + (size_t)row * DD + threadIdx.x * 8;
        float4 a = *(const float4*)xr;
        float4 b = *(const float4*)(xr + 4);
        float s = a.x + a.y + a.z + a.w + b.x + b.y + b.z + b.w;
        float q = a.x * a.x + a.y * a.y + a.z * a.z + a.w * a.w
                + b.x * b.x + b.y * b.y + b.z * b.z + b.w * b.w;
        for (int m = 1; m < 64; m <<= 1) { s += __shfl_xor(s, m); q += __shfl_xor(q, m); }
        if (lane == 0) { ss[w] = s; sq[w] = q; }
        __syncthreads();
        float S = ss[0] + ss[1] + ss[2] + ss[3];
        float Q = sq[0] + sq[1] + sq[2] + sq[3];
        float mu = S * (1.f / DD);
        float ve = Q * (1.f / DD) - mu * mu + 1e-5f;
        float rs = rsqrtf(ve);
        if (threadIdx.x == 0) { muv[row] = mu; sdv[row] = ve * rs; }
        short8_t o;
        o[0] = f2bf((a.x - mu) * rs); o[1] = f2bf((a.y - mu) * rs);
        o[2] = f2bf((a.z - mu) * rs); o[3] = f2bf((a.w - mu) * rs);
        o[4] = f2bf((b.x - mu) * rs); o[5] = f2bf((b.y - mu) * rs);
        o[6] = f2bf((b.z - mu) * rs); o[7] = f2bf((b.w - mu) * rs);
        *(short8_t*)(xn + (size_t)row * DD + threadIdx.x * 8) = o;
    }
}

// ---- k_down: hid = relu(xn @ Wg^T + c2 + bd), 128x128 tile, BK=64, dbuf ----
__global__ __launch_bounds__(256, 2) void k_down(
    const short* __restrict__ xn, const short* __restrict__ Wg,
    const float* __restrict__ c2, const float* __restrict__ bd,
    short* __restrict__ hid)
{
    __shared__ __align__(16) short sA[2][128 * 64];  // 32 KB
    __shared__ __align__(16) short sB[2][128 * 64];  // 32 KB

    // bijective XCD swizzle (nwg=512), n fastest within each XCD chunk
    int bid = blockIdx.x;
    int nb = (bid & 7) * 64 + (bid >> 3);
    const int m0 = (nb >> 2) * 128;
    const int n0 = (nb & 3) * 128;

    const int tid = threadIdx.x, lane = tid & 63, w = tid >> 6;
    const int l15 = lane & 15, rg = lane >> 4;
    const int wm = w >> 1, wn = w & 1;

    auto stage = [&](int b, int kb) {
#pragma unroll
        for (int i = 0; i < 4; i++) {
            int ch = i * 256 + tid;
            int r = ch >> 3, c = ch & 7;
            int co = ((c ^ (r & 7)) << 3);
            gl16(xn + (size_t)(m0 + r) * DD + kb + co,
                 &sA[b][0] + (i * 256 + (w << 6)) * 8);
            gl16(Wg + (size_t)(n0 + r) * DD + kb + co,
                 &sB[b][0] + (i * 256 + (w << 6)) * 8);
        }
    };

    f32x4 acc[4][4];
#pragma unroll
    for (int i = 0; i < 4; i++)
#pragma unroll
        for (int j = 0; j < 4; j++) acc[i][j] = (f32x4){0.f, 0.f, 0.f, 0.f};

    stage(0, 0);
    __syncthreads();

    for (int t = 0; t < 32; t++) {
        int cur = t & 1, nxt = cur ^ 1;
        if (t < 31) stage(nxt, (t + 1) * 64);
#pragma unroll
        for (int kk = 0; kk < 2; kk++) {
            int kc = kk * 4 + rg;
            short8_t af[4], bf[4];
#pragma unroll
            for (int mi = 0; mi < 4; mi++) {
                int rr = wm * 64 + mi * 16 + l15;
                af[mi] = *(const short8_t*)(&sA[cur][0] + rr * 64 + ((kc ^ (rr & 7)) << 3));
            }
#pragma unroll
            for (int ni = 0; ni < 4; ni++) {
                int rr = wn * 64 + ni * 16 + l15;
                bf[ni] = *(const short8_t*)(&sB[cur][0] + rr * 64 + ((kc ^ (rr & 7)) << 3));
            }
#pragma unroll
            for (int mi = 0; mi < 4; mi++)
#pragma unroll
                for (int ni = 0; ni < 4; ni++)
                    acc[mi][ni] = __builtin_amdgcn_mfma_f32_16x16x32_bf16(
                        af[mi], bf[ni], acc[mi][ni], 0, 0, 0);
        }
        __syncthreads();
    }

    // epilogue: + c2 + bd, relu -> hid bf16
#pragma unroll
    for (int ni = 0; ni < 4; ni++) {
        int h = n0 + wn * 64 + ni * 16 + l15;
        float C = c2[h] + bd[h];
#pragma unroll
        for (int mi = 0; mi < 4; mi++) {
#pragma unroll
            for (int j = 0; j < 4; j++) {
                int rowL = wm * 64 + mi * 16 + rg * 4 + j;
                float v = acc[mi][ni][j] + C;
                v = v > 0.f ? v : 0.f;
                hid[(size_t)(m0 + rowL) * HH + h] = f2bf(v);
            }
        }
    }
}

// ---- k_up: out = xn*sd + mu + bu + hid @ Wu^T, 128x128, BK=64, dbuf,
//      coalesced epilogue via padded LDS f32 transpose ----
__global__ __launch_bounds__(256, 2) void k_up(
    const short* __restrict__ xn, const short* __restrict__ hid,
    const short* __restrict__ Wub, const float* __restrict__ bu,
    const float* __restrict__ muv, const float* __restrict__ sdv,
    float* __restrict__ out)
{
    __shared__ __align__(16) char smem[67584];   // K-loop: sA+sB; epilogue: C[128][132] f32
    short* sA = (short*)smem;             // [2][128*64] 32 KB
    short* sB = (short*)(smem + 32768);   // [2][128*64] 32 KB

    // bijective XCD swizzle (nwg=2048), n fastest within each XCD chunk
    int bid = blockIdx.x;
    int nb = (bid & 7) * 256 + (bid >> 3);
    const int m0 = (nb >> 4) * 128;
    const int n0 = (nb & 15) * 128;

    const int tid = threadIdx.x, lane = tid & 63, w = tid >> 6;
    const int l15 = lane & 15, rg = lane >> 4;
    const int wm = w >> 1, wn = w & 1;

    auto stage = [&](int b, int kb) {
#pragma unroll
        for (int i = 0; i < 4; i++) {
            int ch = i * 256 + tid;
            int r = ch >> 3, c = ch & 7;
            int co = ((c ^ (r & 7)) << 3);
            gl16(hid + (size_t)(m0 + r) * HH + kb + co,
                 sA + b * 8192 + (i * 256 + (w << 6)) * 8);
            gl16(Wub + (size_t)(n0 + r) * HH + kb + co,
                 sB + b * 8192 + (i * 256 + (w << 6)) * 8);
        }
    };

    f32x4 acc[4][4];
#pragma unroll
    for (int i = 0; i < 4; i++)
#pragma unroll
        for (int j = 0; j < 4; j++) acc[i][j] = (f32x4){0.f, 0.f, 0.f, 0.f};

    stage(0, 0);
    __syncthreads();

    for (int t = 0; t < 8; t++) {
        int cur = t & 1, nxt = cur ^ 1;
        if (t < 7) stage(nxt, (t + 1) * 64);
#pragma unroll
        for (int kk = 0; kk < 2; kk++) {
            int kc = kk * 4 + rg;
            short8_t af[4], bf[4];
#pragma unroll
            for (int mi = 0; mi < 4; mi++) {
                int rr = wm * 64 + mi * 16 + l15;
                af[mi] = *(const short8_t*)(sA + cur * 8192 + rr * 64 + ((kc ^ (rr & 7)) << 3));
            }
#pragma unroll
            for (int ni = 0; ni < 4; ni++) {
                int rr = wn * 64 + ni * 16 + l15;
                bf[ni] = *(const short8_t*)(sB + cur * 8192 + rr * 64 + ((kc ^ (rr & 7)) << 3));
            }
#pragma unroll
            for (int mi = 0; mi < 4; mi++)
#pragma unroll
                for (int ni = 0; ni < 4; ni++)
                    acc[mi][ni] = __builtin_amdgcn_mfma_f32_16x16x32_bf16(
                        af[mi], bf[ni], acc[mi][ni], 0, 0, 0);
        }
        __syncthreads();
    }

    // ---- epilogue ----
    // early-issue the residual xn loads (latency hides under C-transpose)
    const int erow = tid >> 1, ehalf = tid & 1;
    const size_t rb = (size_t)(m0 + erow) * DD + n0 + ehalf * 64;
    short8_t xnv[8];
#pragma unroll
    for (int i = 0; i < 8; i++) xnv[i] = *(const short8_t*)(xn + rb + i * 8);
    const float mu = muv[m0 + erow];
    const float sd = sdv[m0 + erow];

    // acc -> padded LDS f32 tile (stride 132: bank = (4*row + col)%32, 2-way max)
    float* C = (float*)smem;
#pragma unroll
    for (int ni = 0; ni < 4; ni++)
#pragma unroll
        for (int mi = 0; mi < 4; mi++)
#pragma unroll
            for (int j = 0; j < 4; j++) {
                int row = wm * 64 + mi * 16 + rg * 4 + j;
                int col = wn * 64 + ni * 16 + l15;
                C[row * 132 + col] = acc[mi][ni][j];
            }
    __syncthreads();

    // coalesced combine + store: each thread owns (row, 64-col half)
    const float* Crow = C + erow * 132 + ehalf * 64;
    const float* burow = bu + n0 + ehalf * 64;
#pragma unroll
    for (int i = 0; i < 16; i++) {
        f32x4 c = *(const f32x4*)(Crow + i * 4);
        float4 bv = *(const float4*)(burow + i * 4);
        f32x4 o;
        o[0] = fmaf(bf2f((unsigned short)xnv[i >> 1][(i & 1) * 4 + 0]), sd, mu) + bv.x + c[0];
        o[1] = fmaf(bf2f((unsigned short)xnv[i >> 1][(i & 1) * 4 + 1]), sd, mu) + bv.y + c[1];
        o[2] = fmaf(bf2f((unsigned short)xnv[i >> 1][(i & 1) * 4 + 2]), sd, mu) + bv.z + c[2];
        o[3] = fmaf(bf2f((unsigned short)xnv[i >> 1][(i & 1) * 4 + 3]), sd, mu) + bv.w + c[3];
        *(f32x4*)&out[rb + i * 4] = o;
    }
}

extern "C" void kernel_launch(void* const* d_in, const int* in_sizes, int n_in,
                              void* d_out, int out_size, void* d_ws, size_t ws_size,
                              hipStream_t stream) {
    const float* x     = (const float*)d_in[0];
    const float* gamma = (const float*)d_in[1];
    const float* beta  = (const float*)d_in[2];
    const float* Wd_f  = (const float*)d_in[3];  // [H, D]
    const float* bd    = (const float*)d_in[4];
    const float* Wu_f  = (const float*)d_in[5];  // [D, H]
    const float* bu    = (const float*)d_in[6];

    short* Wg  = (short*)d_ws;                     // 2 MB bf16 [H][D] (Wd*gamma)
    short* Wub = Wg + (size_t)HH * DD;             // 2 MB bf16 [D][H]
    float* c2  = (float*)(Wub + (size_t)DD * HH);  // 2 KB
    float* muv = c2 + HH;                          // 64 KB
    float* sdv = muv + NTOK;                       // 64 KB
    short* hid = (short*)(sdv + NTOK);             // 16 MB bf16 [NTOK][H]
    short* xn  = hid + (size_t)NTOK * HH;          // 64 MB bf16 [NTOK][D]

    k_prep<<<384 + NTOK, 256, 0, stream>>>(Wd_f, gamma, beta, Wu_f, x,
                                           Wg, Wub, c2, xn, muv, sdv);
    k_down<<<(NTOK / 128) * (HH / 128), 256, 0, stream>>>(xn, Wg, c2, bd, hid);
    k_up<<<(NTOK / 128) * (DD / 128), 256, 0, stream>>>(xn, hid, Wub, bu,
                                                        muv, sdv, (float*)d_out);
}